// Round 3
// baseline (109.032 us; speedup 1.0000x reference)
//
#include <hip/hip_runtime.h>
#include <cstddef>

// ExpFilter via linearity: out = scan_t(X @ W^T + b) = scan_t(X) @ W^T + b*c(t)
//   c(t) = (1 - d^(t+1)) / (1 - d),  d = exp(-1)
// K0: split W -> bf16 hi/lo.
// K1: k_filter: Xf = scan_t(X), written as bf16 hi/lo (chunk=64, warmup=32;
//     truncation error <= d^33 ~ 5e-15). Fully parallel, no barriers.
// K2: k_gemm2: out = Xf @ W^T + b*c(t). No LDS, no barriers; W frags in
//     registers, A frags streamed from L3-resident Xf.

#define DECAY  0.36787944117144233f
#define INV1MD 1.5819767068693265f   // 1/(1-d)

typedef __attribute__((ext_vector_type(8))) short short8;
typedef __attribute__((ext_vector_type(2))) short short2v;
typedef __attribute__((ext_vector_type(4))) float f32x4;
typedef __attribute__((ext_vector_type(2))) float f32x2;

static constexpr int T_DIM = 2048, B_DIM = 32, K_DIM = 256, N_DIM = 256;
static constexpr int M_DIM = T_DIM * B_DIM;      // 65536
static constexpr int FCH = 64, FWARM = 32;       // filter chunking

__device__ __forceinline__ float bfbits2f(unsigned short u) {
  unsigned int x = ((unsigned int)u) << 16;
  return __builtin_bit_cast(float, x);
}
__device__ __forceinline__ short f2bf_s(float f) {
  __bf16 h = (__bf16)f;
  return __builtin_bit_cast(short, h);
}

// ---------------- K0: W (fp32 [O][I]) -> W_hi, W_lo bf16 ----------------
__global__ void k_split_w(const float* __restrict__ W, short* __restrict__ Wh,
                          short* __restrict__ Wl) {
  int i = blockIdx.x * 256 + threadIdx.x;
  float w = W[i];
  short h = f2bf_s(w);
  Wh[i] = h;
  Wl[i] = f2bf_s(w - bfbits2f((unsigned short)h));
}

// ---------------- K1: Xf = scan_t(X) -> bf16 hi/lo, plain [T][B][I] ----------------
// grid (T/FCH=32, B/2=16) x 256 thr. Thread owns channels (b, i2..i2+1).
__global__ __launch_bounds__(256)
void k_filter(const float* __restrict__ X, short* __restrict__ Xfh,
              short* __restrict__ Xfl) {
  const int tid = threadIdx.x;
  const int b   = blockIdx.y * 2 + (tid >> 7);
  const int i2  = (tid & 127) * 2;
  const int c   = blockIdx.x;
  const int t0  = c * FCH;
  const int ts  = (c == 0) ? 0 : (t0 - FWARM);
  const float d = DECAY;
  const size_t chbase = (size_t)b * 256 + i2;

  float s0 = 0.f, s1 = 0.f;
  const float* p = X + (size_t)ts * 8192 + chbase;
  #pragma unroll 4
  for (int t = ts; t < t0; ++t) {            // warmup (<=32 steps), no stores
    f32x2 v = *reinterpret_cast<const f32x2*>(p); p += 8192;
    s0 = fmaf(d, s0, v[0]);
    s1 = fmaf(d, s1, v[1]);
  }
  size_t o = (size_t)t0 * 8192 + chbase;
  #pragma unroll 4
  for (int t = 0; t < FCH; ++t) {
    f32x2 v = *reinterpret_cast<const f32x2*>(p); p += 8192;
    s0 = fmaf(d, s0, v[0]);
    s1 = fmaf(d, s1, v[1]);
    short h0 = f2bf_s(s0), h1 = f2bf_s(s1);
    short l0 = f2bf_s(s0 - bfbits2f((unsigned short)h0));
    short l1 = f2bf_s(s1 - bfbits2f((unsigned short)h1));
    short2v hv; hv[0] = h0; hv[1] = h1;
    short2v lv; lv[0] = l0; lv[1] = l1;
    *reinterpret_cast<short2v*>(Xfh + o) = hv;
    *reinterpret_cast<short2v*>(Xfl + o) = lv;
    o += 8192;
  }
}

// ---------------- K2: out = Xf @ W^T + b*c(t) ----------------
// grid (M/16/8=512, 2) x 256 thr = 4 waves. Wave owns 32 cols; 8 row-groups
// per block. No LDS, no barriers. 3-term split-bf16 MFMA.
__global__ __launch_bounds__(256, 2)
void k_gemm2(const short* __restrict__ Xfh, const short* __restrict__ Xfl,
             const short* __restrict__ Wh, const short* __restrict__ Wl,
             const float* __restrict__ bias, float* __restrict__ out) {
  const int tid   = threadIdx.x;
  const int lane  = tid & 63;
  const int wv    = tid >> 6;
  const int row16 = lane & 15;
  const int kq    = lane >> 4;
  const int colbase = blockIdx.y * 128 + wv * 32;

  // W fragments resident: 2 cf x 8 kt, hi+lo = 128 VGPR
  short8 bh[2][8], bl[2][8];
  #pragma unroll
  for (int cf = 0; cf < 2; ++cf) {
    const size_t wrow = (size_t)(colbase + cf * 16 + row16) * 256;
    #pragma unroll
    for (int kt = 0; kt < 8; ++kt) {
      bh[cf][kt] = *reinterpret_cast<const short8*>(Wh + wrow + kt * 32 + kq * 8);
      bl[cf][kt] = *reinterpret_cast<const short8*>(Wl + wrow + kt * 32 + kq * 8);
    }
  }

  for (int r = 0; r < 8; ++r) {
    const int g = blockIdx.x * 8 + r;
    const size_t abase = ((size_t)g * 16 + row16) * 256 + kq * 8;

    short8 ah[8], al[8];
    #pragma unroll
    for (int kt = 0; kt < 8; ++kt) {
      ah[kt] = *reinterpret_cast<const short8*>(Xfh + abase + kt * 32);
      al[kt] = *reinterpret_cast<const short8*>(Xfl + abase + kt * 32);
    }

    f32x4 acc0 = {}, acc1 = {};
    #pragma unroll
    for (int kt = 0; kt < 8; ++kt) {
      acc0 = __builtin_amdgcn_mfma_f32_16x16x32_bf16(ah[kt], bh[0][kt], acc0, 0, 0, 0);
      acc1 = __builtin_amdgcn_mfma_f32_16x16x32_bf16(ah[kt], bh[1][kt], acc1, 0, 0, 0);
      acc0 = __builtin_amdgcn_mfma_f32_16x16x32_bf16(al[kt], bh[0][kt], acc0, 0, 0, 0);
      acc1 = __builtin_amdgcn_mfma_f32_16x16x32_bf16(al[kt], bh[1][kt], acc1, 0, 0, 0);
      acc0 = __builtin_amdgcn_mfma_f32_16x16x32_bf16(ah[kt], bl[0][kt], acc0, 0, 0, 0);
      acc1 = __builtin_amdgcn_mfma_f32_16x16x32_bf16(ah[kt], bl[1][kt], acc1, 0, 0, 0);
    }

    // bias scale: rows of this group share t = g>>1;  d^n = exp(-n)
    const int t = g >> 1;
    const float cfac = (1.f - __expf(-(float)(t + 1))) * INV1MD;

    // C/D layout: col = lane&15, row = kq*4 + j  [validated R1/R2]
    #pragma unroll
    for (int cf = 0; cf < 2; ++cf) {
      const f32x4 a = cf ? acc1 : acc0;
      const int col = colbase + cf * 16 + row16;
      const float bb = bias[col] * cfac;
      #pragma unroll
      for (int j = 0; j < 4; ++j)
        out[((size_t)g * 16 + kq * 4 + j) * 256 + col] = a[j] + bb;
    }
  }
}

// ---------------- fallback (ws too small): naive fp32 ----------------
__global__ void k_fb_gemm(const float* __restrict__ X, const float* __restrict__ W,
                          const float* __restrict__ bias, float* __restrict__ Y) {
  size_t idx = (size_t)blockIdx.x * 256 + threadIdx.x;
  int o = (int)(idx & 255);
  size_t m = idx >> 8;
  const float* x = X + m * 256;
  const float* w = W + (size_t)o * 256;
  float s = bias[o];
  for (int k = 0; k < 256; ++k) s = fmaf(x[k], w[k], s);
  Y[idx] = s;
}
__global__ void k_fb_scan(float* __restrict__ Y) {
  int ch = blockIdx.x * 256 + threadIdx.x;
  float s = 0.f;
  float* p = Y + ch;
  for (int t = 0; t < 2048; ++t) { s = fmaf(DECAY, s, *p); *p = s; p += 8192; }
}

extern "C" void kernel_launch(void* const* d_in, const int* in_sizes, int n_in,
                              void* d_out, int out_size, void* d_ws, size_t ws_size,
                              hipStream_t stream) {
  const float* X    = (const float*)d_in[0];
  const float* W    = (const float*)d_in[1];
  const float* bias = (const float*)d_in[2];
  float* out = (float*)d_out;

  const size_t w_elems  = (size_t)N_DIM * K_DIM;           // 65536
  const size_t xf_elems = (size_t)M_DIM * K_DIM;           // 16.7M
  const size_t need = (2 * w_elems + 2 * xf_elems) * sizeof(short);  // ~64.25 MiB

  if (ws_size >= need) {
    short* Wh  = (short*)d_ws;
    short* Wl  = Wh + w_elems;
    short* Xfh = Wl + w_elems;
    short* Xfl = Xfh + xf_elems;
    k_split_w<<<w_elems / 256, 256, 0, stream>>>(W, Wh, Wl);
    k_filter<<<dim3(T_DIM / FCH, B_DIM / 2), 256, 0, stream>>>(X, Xfh, Xfl);
    k_gemm2<<<dim3(M_DIM / 16 / 8, 2), 256, 0, stream>>>(Xfh, Xfl, Wh, Wl, bias, out);
  } else {
    k_fb_gemm<<<M_DIM, 256, 0, stream>>>(X, W, bias, out);
    k_fb_scan<<<32, 256, 0, stream>>>(out);
  }
}